// Round 6
// baseline (49.140 us; speedup 1.0000x reference)
//
#include <hip/hip_runtime.h>

#define B 2
#define S 512
#define D 256
#define C2L 2.885390081777927f    // 2*log2(e)
#define LOG2E 1.4426950408889634f
#define NEQ 4                     // e-quarters (partial score streams)
#define EQL (D / NEQ)             // 64 e per stream
#define ETILE 32                  // e-tile staged in LDS

// proj: Pt = (q @ W^T) * C2L for 8 rows/block.
// Emits EJ[b][e][i] = exp2(Pt), EN[b][i][e] = exp2(-Pt), and the 8x8
// diagonal score tile (full-e, shifted by -c) into SC stream 0.
__global__ __launch_bounds__(512, 2) void proj_kernel(const float* __restrict__ q,
                                                      const float* __restrict__ W,
                                                      const float* __restrict__ vm,
                                                      float* __restrict__ EJ,
                                                      float* __restrict__ EN,
                                                      float* __restrict__ SC0) {
    __shared__ float qlds[8][D];
    __shared__ float ptl[8][D + 4];
    __shared__ float vml[D];          // -2*vm
    __shared__ float dred[64][9];

    const int t = threadIdx.x;
    const int b = blockIdx.x >> 6;    // 64 blocks per batch
    const int g = blockIdx.x & 63;
    const int i0 = g * 8;

    {   // stage 8 q rows, coalesced float4
        const int row = t >> 6, c4 = (t & 63) * 4;
        *(float4*)&qlds[row][c4] =
            *(const float4*)(q + ((size_t)(b * S + i0 + row)) * D + c4);
    }
    if (t < D) vml[t] = -2.f * vm[t];
    __syncthreads();

    const int e = t & 255, rh = (t >> 8) * 4;
    const float* wr = W + (size_t)e * D;
    float a0 = 0.f, a1 = 0.f, a2 = 0.f, a3 = 0.f;
#pragma unroll 4
    for (int d = 0; d < D; d += 4) {
        float4 w4 = *(const float4*)(wr + d);
        float4 qa = *(const float4*)&qlds[rh + 0][d];
        float4 qb = *(const float4*)&qlds[rh + 1][d];
        float4 qc = *(const float4*)&qlds[rh + 2][d];
        float4 qd = *(const float4*)&qlds[rh + 3][d];
        a0 = fmaf(qa.x, w4.x, fmaf(qa.y, w4.y, fmaf(qa.z, w4.z, fmaf(qa.w, w4.w, a0))));
        a1 = fmaf(qb.x, w4.x, fmaf(qb.y, w4.y, fmaf(qb.z, w4.z, fmaf(qb.w, w4.w, a1))));
        a2 = fmaf(qc.x, w4.x, fmaf(qc.y, w4.y, fmaf(qc.z, w4.z, fmaf(qc.w, w4.w, a2))));
        a3 = fmaf(qd.x, w4.x, fmaf(qd.y, w4.y, fmaf(qd.z, w4.z, fmaf(qd.w, w4.w, a3))));
    }
    a0 *= C2L; a1 *= C2L; a2 *= C2L; a3 *= C2L;
    *(float4*)(EJ + ((size_t)(b * D + e)) * S + i0 + rh) =
        make_float4(__builtin_amdgcn_exp2f(a0), __builtin_amdgcn_exp2f(a1),
                    __builtin_amdgcn_exp2f(a2), __builtin_amdgcn_exp2f(a3));
    EN[((size_t)(b * S + i0 + rh + 0)) * D + e] = __builtin_amdgcn_exp2f(-a0);
    EN[((size_t)(b * S + i0 + rh + 1)) * D + e] = __builtin_amdgcn_exp2f(-a1);
    EN[((size_t)(b * S + i0 + rh + 2)) * D + e] = __builtin_amdgcn_exp2f(-a2);
    EN[((size_t)(b * S + i0 + rh + 3)) * D + e] = __builtin_amdgcn_exp2f(-a3);
    ptl[rh + 0][e] = a0; ptl[rh + 1][e] = a1;
    ptl[rh + 2][e] = a2; ptl[rh + 3][e] = a3;
    __syncthreads();

    // 8x8 diagonal tile, full-e, shifted form a = sum(-2vm)*rcp(1+e^{2dP})
    {
        const int ent = t & 63, r = ent >> 3, jj = ent & 7, ck = t >> 6;
        float acc = 0.f;
#pragma unroll 8
        for (int el = ck * 32; el < ck * 32 + 32; ++el) {
            float x = ptl[jj][el] - ptl[r][el];
            float y = 1.f + __builtin_amdgcn_exp2f(x);
            acc = fmaf(vml[el], __builtin_amdgcn_rcpf(y), acc);
        }
        dred[ent][ck] = acc;
    }
    __syncthreads();
    if (t < 64) {
        float sum = 0.f;
#pragma unroll
        for (int k = 0; k < 8; ++k) sum += dred[t][k];
        SC0[(size_t)b * S * S + (size_t)(i0 + (t >> 3)) * S + i0 + (t & 7)] = sum;
    }
}

// Triangle strips, LDS-staged EJ tiles, 8 rows/thread.
// Block (b, eq, m): A = group m, j in [8m+8, 512) (NA = 504-8m slots);
// B = group 62-m, j in [504-8m, 512) (NB = 8+8m; j == t). NA+NB = 512.
// Groups 0..31 appear only as A, 32..62 only as B, 63 has no strip.
// Stores per-eq partials (shifted by -c_eq); mirror = -a - 2*c_eq.
__global__ __launch_bounds__(512, 2) void score_kernel(const float* __restrict__ EJ,
                                                       const float* __restrict__ EN,
                                                       const float* __restrict__ vm,
                                                       float* __restrict__ SC) {
    __shared__ float buf[ETILE][S];        // 64 KB
    __shared__ float ft[2][ETILE][8];      // row factors exp2(-Pt)
    __shared__ float wlt[ETILE];           // -2*vm
    __shared__ float ceqL;

    const int t = threadIdx.x;
    const int bid = blockIdx.x;
    const int b = bid >> 7;                // 128 blocks per batch
    const int eq = (bid >> 5) & 3;
    const int m = bid & 31;
    const int e0 = eq * EQL;

    const int NA = 504 - 8 * m;
    const int NB = (m == 31) ? 0 : 8 + 8 * m;
    const int rbA = 8 * m, rbB = 496 - 8 * m;

    if (t < 64) {
        float v = vm[e0 + t];
#pragma unroll
        for (int off = 32; off; off >>= 1) v += __shfl_xor(v, off);
        if (t == 0) ceqL = v;
    }

    const bool act = t < NA + NB;
    const bool inA = t < NA;
    const int j = inA ? (8 * m + 8 + t) : t;
    const int g = inA ? 0 : 1;

    float acc[8] = {};
#pragma unroll
    for (int tile = 0; tile < EQL / ETILE; ++tile) {
        const int et = e0 + tile * ETILE;
        {   // stage EJ tile, coalesced float4
            const int c4 = (t & 127) * 4, er = t >> 7;
#pragma unroll
            for (int p = 0; p < 8; ++p) {
                const int el = p * 4 + er;
                *(float4*)&buf[el][c4] =
                    *(const float4*)(EJ + ((size_t)(b * D + et + el)) * S + c4);
            }
        }
        {   // stage row factors + weights
            const int gg = t >> 8, el = (t >> 3) & 31, r = t & 7;
            const int rb = gg ? rbB : rbA;
            ft[gg][el][r] = EN[((size_t)(b * S + rb + r)) * D + et + el];
            if (t < ETILE) wlt[t] = -2.f * vm[et + t];
        }
        __syncthreads();
        if (act) {
#pragma unroll 8
            for (int el = 0; el < ETILE; ++el) {
                float ev = buf[el][j];
                float w = wlt[el];
                float4 fa = *(const float4*)&ft[g][el][0];
                float4 fb = *(const float4*)&ft[g][el][4];
                acc[0] = fmaf(w, __builtin_amdgcn_rcpf(fmaf(ev, fa.x, 1.f)), acc[0]);
                acc[1] = fmaf(w, __builtin_amdgcn_rcpf(fmaf(ev, fa.y, 1.f)), acc[1]);
                acc[2] = fmaf(w, __builtin_amdgcn_rcpf(fmaf(ev, fa.z, 1.f)), acc[2]);
                acc[3] = fmaf(w, __builtin_amdgcn_rcpf(fmaf(ev, fa.w, 1.f)), acc[3]);
                acc[4] = fmaf(w, __builtin_amdgcn_rcpf(fmaf(ev, fb.x, 1.f)), acc[4]);
                acc[5] = fmaf(w, __builtin_amdgcn_rcpf(fmaf(ev, fb.y, 1.f)), acc[5]);
                acc[6] = fmaf(w, __builtin_amdgcn_rcpf(fmaf(ev, fb.z, 1.f)), acc[6]);
                acc[7] = fmaf(w, __builtin_amdgcn_rcpf(fmaf(ev, fb.w, 1.f)), acc[7]);
            }
        }
        __syncthreads();
    }
    if (act) {
        const float ceq = ceqL;
        const int rb = inA ? rbA : rbB;
        float* sb = SC + ((size_t)eq * B + b) * S * S;
#pragma unroll
        for (int k = 0; k < 8; ++k) sb[(size_t)(rb + k) * S + j] = acc[k];
        *(float4*)&sb[(size_t)j * S + rb] =
            make_float4(fmaf(-2.f, ceq, -acc[0]), fmaf(-2.f, ceq, -acc[1]),
                        fmaf(-2.f, ceq, -acc[2]), fmaf(-2.f, ceq, -acc[3]));
        *(float4*)&sb[(size_t)j * S + rb + 4] =
            make_float4(fmaf(-2.f, ceq, -acc[4]), fmaf(-2.f, ceq, -acc[5]),
                        fmaf(-2.f, ceq, -acc[6]), fmaf(-2.f, ceq, -acc[7]));
    }
}

// Softmax over summed partial streams (diag columns: stream 0 only) + context.
__global__ __launch_bounds__(512) void softctx_kernel(const float* __restrict__ SC,
                                                      const float* __restrict__ value,
                                                      float* __restrict__ att,
                                                      float* __restrict__ ctx) {
    __shared__ float a4[S][4];
    __shared__ float part[4][8][64][4];
    __shared__ float redm[4][2], reds[4][2];

    const int t = threadIdx.x;
    const int b = blockIdx.x >> 7;
    const int i0 = (blockIdx.x & 127) * 4;
    const size_t BSS = (size_t)B * S * S;

    {
        const int row = t >> 7, jr = t & 127;
        const int lane = t & 63, half = (t >> 6) & 1;
        const int i = i0 + row, gi = i >> 3;
        const float* s0 = SC + (size_t)(b * S + i) * S;
        float v[4];
#pragma unroll
        for (int o = 0; o < 4; ++o) {
            const int j = jr + o * 128;
            float v0 = s0[j];
            float vs = v0 + s0[j + BSS] + s0[j + 2 * BSS] + s0[j + 3 * BSS];
            v[o] = ((j >> 3) == gi) ? v0 : vs;
        }
        float lm = fmaxf(fmaxf(v[0], v[1]), fmaxf(v[2], v[3]));
#pragma unroll
        for (int off = 32; off; off >>= 1) lm = fmaxf(lm, __shfl_xor(lm, off));
        if (lane == 0) redm[row][half] = lm;
        __syncthreads();
        float mx = fmaxf(redm[row][0], redm[row][1]);
        float p0 = __builtin_amdgcn_exp2f((v[0] - mx) * LOG2E);
        float p1 = __builtin_amdgcn_exp2f((v[1] - mx) * LOG2E);
        float p2 = __builtin_amdgcn_exp2f((v[2] - mx) * LOG2E);
        float p3 = __builtin_amdgcn_exp2f((v[3] - mx) * LOG2E);
        float ls = (p0 + p1) + (p2 + p3);
#pragma unroll
        for (int off = 32; off; off >>= 1) ls += __shfl_xor(ls, off);
        if (lane == 0) reds[row][half] = ls;
        __syncthreads();
        float rinv = __builtin_amdgcn_rcpf(reds[row][0] + reds[row][1]);
        p0 *= rinv; p1 *= rinv; p2 *= rinv; p3 *= rinv;
        float* arow = att + (size_t)(b * S + i) * S;
        arow[jr] = p0; arow[jr + 128] = p1; arow[jr + 256] = p2; arow[jr + 384] = p3;
        a4[jr][row] = p0; a4[jr + 128][row] = p1;
        a4[jr + 256][row] = p2; a4[jr + 384][row] = p3;
    }
    __syncthreads();

    {
        const int dq = t & 63, js = t >> 6;
        float4 acc0 = {}, acc1 = {}, acc2 = {}, acc3 = {};
        const float* vb = value + (size_t)b * S * D + (size_t)dq * 4;
#pragma unroll 4
        for (int jj = 0; jj < 64; ++jj) {
            int j = js * 64 + jj;
            float4 v = *(const float4*)(vb + (size_t)j * D);
            float w0 = a4[j][0], w1 = a4[j][1], w2 = a4[j][2], w3 = a4[j][3];
            acc0.x = fmaf(w0, v.x, acc0.x); acc0.y = fmaf(w0, v.y, acc0.y);
            acc0.z = fmaf(w0, v.z, acc0.z); acc0.w = fmaf(w0, v.w, acc0.w);
            acc1.x = fmaf(w1, v.x, acc1.x); acc1.y = fmaf(w1, v.y, acc1.y);
            acc1.z = fmaf(w1, v.z, acc1.z); acc1.w = fmaf(w1, v.w, acc1.w);
            acc2.x = fmaf(w2, v.x, acc2.x); acc2.y = fmaf(w2, v.y, acc2.y);
            acc2.z = fmaf(w2, v.z, acc2.z); acc2.w = fmaf(w2, v.w, acc2.w);
            acc3.x = fmaf(w3, v.x, acc3.x); acc3.y = fmaf(w3, v.y, acc3.y);
            acc3.z = fmaf(w3, v.z, acc3.z); acc3.w = fmaf(w3, v.w, acc3.w);
        }
        *(float4*)&part[0][js][dq][0] = acc0;
        *(float4*)&part[1][js][dq][0] = acc1;
        *(float4*)&part[2][js][dq][0] = acc2;
        *(float4*)&part[3][js][dq][0] = acc3;
    }
    __syncthreads();
    if (t < 256) {
        const int row = t >> 6, dq = t & 63;
        float4 sum = {};
#pragma unroll
        for (int js = 0; js < 8; ++js) {
            float4 p = *(const float4*)&part[row][js][dq][0];
            sum.x += p.x; sum.y += p.y; sum.z += p.z; sum.w += p.w;
        }
        *(float4*)(ctx + (size_t)(b * S + i0 + row) * D + (size_t)dq * 4) = sum;
    }
}

extern "C" void kernel_launch(void* const* d_in, const int* in_sizes, int n_in,
                              void* d_out, int out_size, void* d_ws, size_t ws_size,
                              hipStream_t stream) {
    const float* q = (const float*)d_in[0];
    // d_in[1] = key (unused by the reference)
    const float* value = (const float*)d_in[2];
    const float* W = (const float*)d_in[3];
    const float* vm = (const float*)d_in[4];

    float* ctx = (float*)d_out;                    // [B,S,D]
    float* att = ctx + (size_t)B * S * D;          // [B,S,S]
    float* EJ = (float*)d_ws;                      // [B,D,S] exp2(Pt), 1 MB
    float* EN = EJ + (size_t)B * D * S;            // [B,S,D] exp2(-Pt), 1 MB
    float* SC = EN + (size_t)B * S * D;            // [NEQ][B,S,S] partials, 8 MB

    proj_kernel<<<B * 64, 512, 0, stream>>>(q, W, vm, EJ, EN, SC);
    score_kernel<<<B * 128, 512, 0, stream>>>(EJ, EN, vm, SC);
    softctx_kernel<<<B * 128, 512, 0, stream>>>(SC, value, att, ctx);
}

// Round 7
// 48.427 us; speedup vs baseline: 1.0147x; 1.0147x over previous
//
#include <hip/hip_runtime.h>

#define B 2
#define S 512
#define D 256
#define C2L 2.885390081777927f    // 2*log2(e)
#define LOG2E 1.4426950408889634f

// proj: Pt = (q @ W^T) * C2L.
//   EJ[b][e][i] = exp2(Pt)   (e-major: fused kernel j-streams, coalesced)
//   EN[b][i][e] = exp2(-Pt)  (row-major: fused kernel row factors, coalesced)
__global__ __launch_bounds__(256) void proj_kernel(const float* __restrict__ q,
                                                   const float* __restrict__ W,
                                                   float* __restrict__ EJ,
                                                   float* __restrict__ EN) {
    __shared__ float qlds[4 * D];
    const int t = threadIdx.x;
    const int b = blockIdx.x / (S / 4);
    const int i0 = (blockIdx.x % (S / 4)) * 4;
    const float* qbase = q + (size_t)(b * S + i0) * D;
    for (int idx = t; idx < 4 * D; idx += 256) qlds[idx] = qbase[idx];
    __syncthreads();
    const float* wr = W + (size_t)t * D;
    float a0 = 0.f, a1 = 0.f, a2 = 0.f, a3 = 0.f;
#pragma unroll 4
    for (int d = 0; d < D; ++d) {
        float w = wr[d];
        a0 = fmaf(qlds[d], w, a0);
        a1 = fmaf(qlds[D + d], w, a1);
        a2 = fmaf(qlds[2 * D + d], w, a2);
        a3 = fmaf(qlds[3 * D + d], w, a3);
    }
    a0 *= C2L; a1 *= C2L; a2 *= C2L; a3 *= C2L;
    float* ej = EJ + (size_t)(b * D + t) * S + i0;
    *(float4*)ej = make_float4(__builtin_amdgcn_exp2f(a0), __builtin_amdgcn_exp2f(a1),
                               __builtin_amdgcn_exp2f(a2), __builtin_amdgcn_exp2f(a3));
    EN[(size_t)(b * S + i0 + 0) * D + t] = __builtin_amdgcn_exp2f(-a0);
    EN[(size_t)(b * S + i0 + 1) * D + t] = __builtin_amdgcn_exp2f(-a1);
    EN[(size_t)(b * S + i0 + 2) * D + t] = __builtin_amdgcn_exp2f(-a2);
    EN[(size_t)(b * S + i0 + 3) * D + t] = __builtin_amdgcn_exp2f(-a3);
}

// Fused score + softmax + context. Block = 4 rows, 512 threads, thread t = column j.
// Scores live in registers end-to-end; softmax is a cross-thread reduce; only the
// normalized attention row touches LDS/global. No score scratch traffic at all.
__global__ __launch_bounds__(512) void fused_kernel(const float* __restrict__ EJ,
                                                    const float* __restrict__ EN,
                                                    const float* __restrict__ vm,
                                                    const float* __restrict__ value,
                                                    float* __restrict__ att,
                                                    float* __restrict__ ctx) {
    __shared__ float en4[D][4];          // exp2(-Pt) for the 4 rows
    __shared__ float wl[D];              // -2*vm
    __shared__ float a4[S][4];           // normalized attention (for ctx phase)
    __shared__ float part[4][8][64][4];  // ctx partials
    __shared__ float redm[4][8], reds[4][8];

    const int t = threadIdx.x;
    const int b = blockIdx.x >> 7;           // S/4 = 128 blocks per batch
    const int i0 = (blockIdx.x & 127) * 4;

    if (t < D) wl[t] = -2.f * vm[t];
    {
        const int e = t & 255, r2 = (t >> 8) * 2;
        en4[e][r2]     = EN[((size_t)(b * S + i0 + r2)) * D + e];
        en4[e][r2 + 1] = EN[((size_t)(b * S + i0 + r2 + 1)) * D + e];
    }
    __syncthreads();

    // ---- score phase: s'[r] = sum_e (-2 vm_e) * sigma(2(Pj - Pr))  (shift cancels)
    float acc[4] = {};
    const float* ejp = EJ + (size_t)b * D * S + t;
#pragma unroll 8
    for (int e = 0; e < D; ++e) {
        float ev = ejp[(size_t)e * S];
        float w = wl[e];
        float4 f = *(const float4*)&en4[e][0];   // uniform address -> broadcast
        float y0 = fmaf(ev, f.x, 1.f);
        float y1 = fmaf(ev, f.y, 1.f);
        float y2 = fmaf(ev, f.z, 1.f);
        float y3 = fmaf(ev, f.w, 1.f);
        float r0 = __builtin_amdgcn_rcpf(y0);                            // trans pipe
        float r2v = __builtin_amdgcn_rcpf(y2);                           // trans pipe
        float r1 = __uint_as_float(0x7EF311C3u - __float_as_uint(y1));   // VALU pipe
        r1 = r1 * fmaf(-y1, r1, 2.f);
        r1 = r1 * fmaf(-y1, r1, 2.f);
        float r3 = __uint_as_float(0x7EF311C3u - __float_as_uint(y3));   // VALU pipe
        r3 = r3 * fmaf(-y3, r3, 2.f);
        r3 = r3 * fmaf(-y3, r3, 2.f);
        acc[0] = fmaf(w, r0, acc[0]);
        acc[1] = fmaf(w, r1, acc[1]);
        acc[2] = fmaf(w, r2v, acc[2]);
        acc[3] = fmaf(w, r3, acc[3]);
    }

    // ---- softmax over j (one value per thread per row, 8 waves)
    const int lane = t & 63, wv = t >> 6;
#pragma unroll
    for (int r = 0; r < 4; ++r) {
        float lm = acc[r];
#pragma unroll
        for (int off = 32; off; off >>= 1) lm = fmaxf(lm, __shfl_xor(lm, off));
        if (lane == 0) redm[r][wv] = lm;
    }
    __syncthreads();
    float p[4];
#pragma unroll
    for (int r = 0; r < 4; ++r) {
        float m = redm[r][0];
#pragma unroll
        for (int w = 1; w < 8; ++w) m = fmaxf(m, redm[r][w]);
        p[r] = __builtin_amdgcn_exp2f((acc[r] - m) * LOG2E);
        float ls = p[r];
#pragma unroll
        for (int off = 32; off; off >>= 1) ls += __shfl_xor(ls, off);
        if (lane == 0) reds[r][wv] = ls;
    }
    __syncthreads();
#pragma unroll
    for (int r = 0; r < 4; ++r) {
        float s = 0.f;
#pragma unroll
        for (int w = 0; w < 8; ++w) s += reds[r][w];
        float a = p[r] * __builtin_amdgcn_rcpf(s);
        a4[t][r] = a;
        att[(size_t)(b * S + i0 + r) * S + t] = a;
    }
    __syncthreads();

    // ---- context: thread -> (dq = t&63, js = t>>6); value read once per block
    {
        const int dq = t & 63, js = t >> 6;
        float4 acc0 = {}, acc1 = {}, acc2 = {}, acc3 = {};
        const float* vb = value + (size_t)b * S * D + (size_t)dq * 4;
#pragma unroll 4
        for (int jj = 0; jj < 64; ++jj) {
            int j = js * 64 + jj;
            float4 v = *(const float4*)(vb + (size_t)j * D);
            float w0 = a4[j][0], w1 = a4[j][1], w2 = a4[j][2], w3 = a4[j][3];
            acc0.x = fmaf(w0, v.x, acc0.x); acc0.y = fmaf(w0, v.y, acc0.y);
            acc0.z = fmaf(w0, v.z, acc0.z); acc0.w = fmaf(w0, v.w, acc0.w);
            acc1.x = fmaf(w1, v.x, acc1.x); acc1.y = fmaf(w1, v.y, acc1.y);
            acc1.z = fmaf(w1, v.z, acc1.z); acc1.w = fmaf(w1, v.w, acc1.w);
            acc2.x = fmaf(w2, v.x, acc2.x); acc2.y = fmaf(w2, v.y, acc2.y);
            acc2.z = fmaf(w2, v.z, acc2.z); acc2.w = fmaf(w2, v.w, acc2.w);
            acc3.x = fmaf(w3, v.x, acc3.x); acc3.y = fmaf(w3, v.y, acc3.y);
            acc3.z = fmaf(w3, v.z, acc3.z); acc3.w = fmaf(w3, v.w, acc3.w);
        }
        *(float4*)&part[0][js][dq][0] = acc0;
        *(float4*)&part[1][js][dq][0] = acc1;
        *(float4*)&part[2][js][dq][0] = acc2;
        *(float4*)&part[3][js][dq][0] = acc3;
    }
    __syncthreads();
    if (t < 256) {
        const int row = t >> 6, dq = t & 63;
        float4 sum = {};
#pragma unroll
        for (int js = 0; js < 8; ++js) {
            float4 pt = *(const float4*)&part[row][js][dq][0];
            sum.x += pt.x; sum.y += pt.y; sum.z += pt.z; sum.w += pt.w;
        }
        *(float4*)(ctx + (size_t)(b * S + i0 + row) * D + (size_t)dq * 4) = sum;
    }
}

extern "C" void kernel_launch(void* const* d_in, const int* in_sizes, int n_in,
                              void* d_out, int out_size, void* d_ws, size_t ws_size,
                              hipStream_t stream) {
    const float* q = (const float*)d_in[0];
    // d_in[1] = key (unused by the reference)
    const float* value = (const float*)d_in[2];
    const float* W = (const float*)d_in[3];
    const float* vm = (const float*)d_in[4];

    float* ctx = (float*)d_out;                    // [B,S,D]
    float* att = ctx + (size_t)B * S * D;          // [B,S,S]
    float* EJ = (float*)d_ws;                      // [B,D,S] exp2(Pt), 1 MB
    float* EN = EJ + (size_t)B * D * S;            // [B,S,D] exp2(-Pt), 1 MB

    proj_kernel<<<B * (S / 4), 256, 0, stream>>>(q, W, EJ, EN);
    fused_kernel<<<B * (S / 4), 512, 0, stream>>>(EJ, EN, vm, value, att, ctx);
}